// Round 3
// baseline (206.813 us; speedup 1.0000x reference)
//
#include <hip/hip_runtime.h>

static constexpr int B_ = 256;
static constexpr int R_ = 1152;
static constexpr int C_ = 10;
static constexpr int O_ = 16;
static constexpr int I_ = 8;
static constexpr int SCO = C_ * O_;   // 160
static constexpr int K_ = R_ * I_;    // 9216
static constexpr int NB = 160;        // grid: <= CU count, 1 block/CU via LDS

typedef short bf16x8 __attribute__((ext_vector_type(8)));
typedef float f32x4  __attribute__((ext_vector_type(4)));

__device__ __forceinline__ unsigned short f2bf(float f) {
  union { float f; unsigned int u; } c; c.f = f;
  const unsigned int u = c.u;
  return (unsigned short)((u + 0x7fffu + ((u >> 16) & 1u)) >> 16);  // RNE
}
__device__ __forceinline__ float bf2f(unsigned short h) {
  union { unsigned int u; float f; } c; c.u = ((unsigned int)h) << 16; return c.f;
}

// Manual grid barrier: agent-scope release add + acquire-load spin.
// Release side emits L2 writeback (publishes plain stores), acquire side
// emits L2/L1 invalidate (drops stale clean lines) -> cross-XCD safe (G16).
// Spin guard: if co-residency were ever violated we produce a wrong answer
// instead of hanging the harness.
__device__ __forceinline__ void gsync(unsigned int* bar, unsigned int target) {
  __syncthreads();
  if (threadIdx.x == 0) {
    __hip_atomic_fetch_add(bar, 1u, __ATOMIC_ACQ_REL, __HIP_MEMORY_SCOPE_AGENT);
    int guard = 0;
    while (__hip_atomic_load(bar, __ATOMIC_ACQUIRE, __HIP_MEMORY_SCOPE_AGENT) < target) {
      __builtin_amdgcn_s_sleep(2);
      if (++guard > (1 << 22)) break;
    }
  }
  __syncthreads();
}

// ===========================================================================
// mega: ONE plain launch, 160 blocks x 512 threads, 82.5 KB LDS (1 block/CU).
// Phases: prep -> [gemm -> pv] x2 -> gemm(final), separated by gsync.
// All buffers write-once-per-address per execution (vb/wb2 ping-pong); Z is
// accumulated/read via device-scope atomics.
// ===========================================================================
__global__ __launch_bounds__(512, 1) void mega(
    const float* __restrict__ x, const float* __restrict__ W,
    float* __restrict__ out, unsigned int* __restrict__ bar,
    float* __restrict__ bvec, float* __restrict__ Z,
    unsigned short* __restrict__ xb, unsigned short* __restrict__ wraw,
    unsigned short* __restrict__ xT,
    unsigned short* __restrict__ vb0, unsigned short* __restrict__ vb1,
    unsigned short* __restrict__ wb2a, unsigned short* __restrict__ wb2b) {
  __shared__ __align__(16) unsigned char smem[82560];
  const int bx = blockIdx.x;
  const int t = threadIdx.x;
  const int lane = t & 63;
  const int w = __builtin_amdgcn_readfirstlane(t >> 6);   // 0..7
  const int mrow = lane & 15, quad = lane >> 4;

  // ---------------- prep: W -> wraw; x -> xb + xT (LDS transpose) ----------
  {
    // W: 368640 float4 total = 2304 per block (exact)
    const float4* wf = (const float4*)W;
    ushort4* wr = (ushort4*)wraw;
    for (int idx = t; idx < 2304; idx += 512) {
      const int j = bx * 2304 + idx;
      const float4 v4 = wf[j];
      ushort4 r4;
      r4.x = f2bf(v4.x); r4.y = f2bf(v4.y); r4.z = f2bf(v4.z); r4.w = f2bf(v4.w);
      wr[j] = r4;
    }
    if (bx == 0 && t < 32) Z[t] = 0.0f;      // Z[10..29] accumulated by pv
    // x: 256 units of (64 b x 18 r); blocks 0..95 take two units
    float* sx = (float*)smem;                // 144 x 68 floats = 39168 B
    for (int u = bx; u < 256; u += NB) {
      const int bq = u & 3, rseg = u >> 2;
      const int rbase = rseg * 18;
      __syncthreads();                       // sx reuse guard (2nd trip)
      for (int idx = t; idx < 64 * 36; idx += 512) {
        const int b = idx / 36, f4 = idx - b * 36;
        const size_t off = (size_t)(bq * 64 + b) * K_ + rbase * I_ + f4 * 4;
        const float4 val = *(const float4*)(x + off);
        ushort4 o4;
        o4.x = f2bf(val.x); o4.y = f2bf(val.y); o4.z = f2bf(val.z); o4.w = f2bf(val.w);
        *(ushort4*)(xb + off) = o4;
        const int rr = f4 >> 1, i4 = (f4 & 1) * 4;
        sx[(rr * 8 + i4 + 0) * 68 + b] = val.x;
        sx[(rr * 8 + i4 + 1) * 68 + b] = val.y;
        sx[(rr * 8 + i4 + 2) * 68 + b] = val.z;
        sx[(rr * 8 + i4 + 3) * 68 + b] = val.w;
      }
      __syncthreads();
      for (int row = w * 18; row < w * 18 + 18; ++row)
        xT[(size_t)(rseg * 144 + row) * 256 + bq * 64 + lane] = f2bf(sx[row * 68 + lane]);
    }
  }
  gsync(bar, NB);

  for (int it = 0; it < 3; ++it) {
    // ------------- gemm: 160 blocks, full-K, 8-wave LDS reduce -------------
    {
      float* sred = (float*)smem;            // 8 x 272 floats
      float* szed = (float*)(smem + 16384);  // 10 floats
      const unsigned short* Bm = (it == 0) ? wraw : (it == 1 ? wb2a : wb2b);
      const int g = (bx & 7) * 20 + (bx >> 3);  // XCD: 2 mtiles x 10 c (3.5 MB)
      const int mtile = g / 10, c = g - mtile * 10;
      const int m0 = mtile * 16;
      const unsigned short* ap = xb + (size_t)(m0 + mrow) * K_ + w * 1152 + quad * 8;
      const unsigned short* bp = Bm + ((size_t)(w * 144 + quad) * C_ + c) * 128 + mrow * 8;
      if (t < 10) szed[t] = (it == 0) ? 1152.0f
                                      : atomicAdd(&Z[it * 10 + t], 0.0f);  // coherent
      f32x4 acc = {0.0f, 0.0f, 0.0f, 0.0f};
#pragma unroll 6
      for (int kk = 0; kk < 36; ++kk) {
        const bf16x8 a = *(const bf16x8*)(ap + kk * 32);
        const bf16x8 b = *(const bf16x8*)(bp + (size_t)kk * 5120);
        acc = __builtin_amdgcn_mfma_f32_16x16x32_bf16(a, b, acc, 0, 0, 0);
      }
#pragma unroll
      for (int rg = 0; rg < 4; ++rg)
        sred[w * 272 + mrow * 17 + quad * 4 + rg] = acc[rg];
      __syncthreads();
      if (t < 256) {
        int m, n;
        if (it == 2) { m = t >> 4; n = t & 15; } else { n = t >> 4; m = t & 15; }
        const int e = n * 17 + m;
        const float ss = ((sred[0 * 272 + e] + sred[1 * 272 + e]) +
                          (sred[2 * 272 + e] + sred[3 * 272 + e])) +
                         ((sred[4 * 272 + e] + sred[5 * 272 + e]) +
                          (sred[6 * 272 + e] + sred[7 * 272 + e]));
        const float s = ss / szed[c];
        const float v = s * fabsf(s) / (1.0f + s * s);   // squash
        if (it == 2) out[(size_t)(m0 + m) * SCO + c * 16 + n] = v;
        else {
          unsigned short* vbw = (it == 0) ? vb0 : vb1;   // ping-pong
          vbw[(size_t)(c * 16 + n) * 256 + m0 + m] = f2bf(v);
        }
      }
    }
    if (it == 2) break;
    gsync(bar, (unsigned)NB * (2 * it + 2));

    // ------------- pv: 72 blocks x 16 r, fused routing update --------------
    if (bx < 72) {
      unsigned short* svb = (unsigned short*)smem;       // 80 KB staged vb
      float* sp = (float*)smem;                          // alias: P tiles 80 KB
      float* sbs = (float*)(smem + 81920);               // 160 floats
      const unsigned short* vbr = (it == 0) ? vb0 : vb1;
      unsigned short* wb2w = (it == 0) ? wb2a : wb2b;
      const int seg = (bx & 7) * 9 + (bx >> 3);          // 0..71, XCD-swizzled
      const int r0 = seg * 16;
      const unsigned short* ap = xT + (size_t)(seg * 128 + w * 16 + mrow) * 256 + quad * 8;
      bf16x8 afr[8];
#pragma unroll
      for (int kk = 0; kk < 8; ++kk) afr[kk] = *(const bf16x8*)(ap + kk * 32);
      {  // stage vb -> LDS, XOR-swizzled (b128 reads conflict-reduced)
        const char* src = (const char*)vbr;
        char* dst = (char*)svb;
#pragma unroll
        for (int i = 0; i < 10; ++i) {
          const int ci = i * 512 + t;
          const int lin = ci * 16;
          const int n = ci >> 5;
          *(bf16x8*)(dst + (lin ^ ((n & 7) << 4))) = *(const bf16x8*)(src + lin);
        }
      }
      __syncthreads();
      f32x4 acc[10];
#pragma unroll
      for (int c = 0; c < 10; ++c) acc[c] = (f32x4){0.0f, 0.0f, 0.0f, 0.0f};
#pragma unroll
      for (int c = 0; c < 10; ++c) {
        const int n = c * 16 + mrow;
        const int base = n * 512 + quad * 16;
#pragma unroll
        for (int kk = 0; kk < 8; ++kk) {
          const bf16x8 b = *(const bf16x8*)((const char*)svb +
                            ((base + kk * 64) ^ ((n & 7) << 4)));
          acc[c] = __builtin_amdgcn_mfma_f32_16x16x32_bf16(afr[kk], b, acc[c], 0, 0, 0);
        }
      }
      __syncthreads();                       // svb reads done before sp overwrite
#pragma unroll
      for (int c = 0; c < 10; ++c)
#pragma unroll
        for (int rg = 0; rg < 4; ++rg) {
          const int ml = w * 16 + quad * 4 + rg;         // m = rl*8+i, 0..127
          sp[(c * 16 + (ml >> 3)) * 128 + mrow * 8 + (ml & 7)] = acc[c][rg];
        }
      __syncthreads();
      const int p16 = t >> 5, l32 = t & 31;
#pragma unroll
      for (int ch = 0; ch < 10; ++ch) {
        const int pair = ch * 16 + p16;                  // 0..159
        const int rl = pair / 10, c = pair - rl * 10;
        const float4 pv = *(const float4*)&sp[(c * 16 + rl) * 128 + l32 * 4];
        const float4 wv = *(const float4*)(W + (size_t)(r0 + rl) * 1280 + c * 128 + l32 * 4);
        float prod = wv.x * pv.x + wv.y * pv.y + wv.z * pv.z + wv.w * pv.w;
        prod += __shfl_xor(prod, 1);  prod += __shfl_xor(prod, 2);
        prod += __shfl_xor(prod, 4);  prod += __shfl_xor(prod, 8);
        prod += __shfl_xor(prod, 16);
        if (l32 == 0) sbs[rl * 10 + c] = prod;
      }
      __syncthreads();
      if (t < 160) {                                     // routing update + exp
        const int rl = t / 10, c = t - rl * 10;
        const int r = r0 + rl;
        float b = sbs[t] * (1.0f / 256.0f);
        if (it != 0) b += bvec[r * C_ + c];
        bvec[r * C_ + c] = b;
        sbs[t] = expf(b);                                // |b| << 1: safe
      }
      __syncthreads();
      if (t < 10) {
        float z = 0.0f;
#pragma unroll
        for (int rl = 0; rl < 16; ++rl) z += sbs[rl * 10 + t];
        atomicAdd(&Z[(it + 1) * 10 + t], z);
      }
      // regen wb2 slice = bf16(wraw * e): 16 r x 1280 = 2560 ushort8
#pragma unroll
      for (int i = 0; i < 5; ++i) {
        const int base = i * 4096 + t * 8;
        const int rl = base / 1280, rem2 = base - rl * 1280;
        const int c = rem2 >> 7;
        const float e = sbs[rl * 10 + c];
        const size_t off = ((size_t)(r0 + rl) * C_ + c) * 128 + (rem2 & 127);
        const bf16x8 wv8 = *(const bf16x8*)(wraw + off);
        bf16x8 o8;
#pragma unroll
        for (int j = 0; j < 8; ++j)
          o8[j] = (short)f2bf(bf2f((unsigned short)wv8[j]) * e);
        *(bf16x8*)(wb2w + off) = o8;
      }
    }
    gsync(bar, (unsigned)NB * (2 * it + 3));
  }
}

extern "C" void kernel_launch(void* const* d_in, const int* in_sizes, int n_in,
                              void* d_out, int out_size, void* d_ws, size_t ws_size,
                              hipStream_t stream) {
  const float* x = (const float*)d_in[0];  // (B,R,I) fp32
  const float* W = (const float*)d_in[1];  // (R,C,O,I) fp32
  float* out = (float*)d_out;              // (B,C,O,1) fp32

  unsigned int* bar = (unsigned int*)d_ws;                 // 16 u32
  float* bvec = (float*)d_ws + 16;                         // 11520
  float* Z    = bvec + R_ * C_;                            // 32
  unsigned short* xb   = (unsigned short*)(Z + 32);        // B*K      = 2359296
  unsigned short* wraw = xb + (size_t)B_ * K_;             // R*C*O*I  = 1474560
  unsigned short* xT   = wraw + (size_t)R_ * C_ * O_ * I_; // R*8*256  = 2359296
  unsigned short* vb0  = xT + (size_t)R_ * 8 * 256;        // 160*256
  unsigned short* vb1  = vb0 + (size_t)160 * 256;
  unsigned short* wb2a = vb1 + (size_t)160 * 256;          // R*C*O*I
  unsigned short* wb2b = wb2a + (size_t)R_ * C_ * O_ * I_;

  hipMemsetAsync(bar, 0, 64, stream);                      // capture-safe
  mega<<<NB, 512, 0, stream>>>(x, W, out, bar, bvec, Z, xb, wraw, xT,
                               vb0, vb1, wb2a, wb2b);
}